// Round 12
// baseline (3447.396 us; speedup 1.0000x reference)
//
#include <hip/hip_runtime.h>

typedef _Float16 h16;
typedef _Float16 h16x2 __attribute__((ext_vector_type(2)));
typedef _Float16 h16x4 __attribute__((ext_vector_type(4)));
typedef _Float16 h16x8 __attribute__((ext_vector_type(8)));
typedef float f32x4 __attribute__((ext_vector_type(4)));

static constexpr int NN   = 20000;   // nodes
static constexpr int NPAD = 20224;   // padded to 256-row tiles (79*256)
static constexpr int NE0  = 120000;  // raw edges
static constexpr int NE   = 140000;  // + self loops
static constexpr int NG   = 512;     // graphs
static constexpr int FIN  = 300;
static constexpr int K1P  = 384;     // FIN padded to K%32==0
static constexpr int CD   = 256;     // channels per head
static constexpr float SLOPE = 0.2f;

#define GLDS16(gsrc, ldst)                                                              \
  __builtin_amdgcn_global_load_lds(                                                    \
      (const __attribute__((address_space(1))) unsigned int*)(gsrc),                    \
      (__attribute__((address_space(3))) unsigned int*)(ldst), 16, 0, 0)

#define MFMA16(a, b, c) __builtin_amdgcn_mfma_f32_16x16x32_f16(a, b, c, 0, 0, 0)

// ---------- input conversion ----------
__global__ __launch_bounds__(256) void fill_x_kernel(const float* __restrict__ x, h16* __restrict__ a1) {
  int r = blockIdx.x;
  for (int c = threadIdx.x; c < K1P; c += 256) {
    float v = (r < NN && c < FIN) ? x[(size_t)r * FIN + c] : 0.f;
    a1[(size_t)r * K1P + c] = (h16)v;
  }
}

__global__ __launch_bounds__(256) void conv_w2_kernel(const float* __restrict__ wl, const float* __restrict__ wr,
                                                      h16* __restrict__ o, int rows, int cols, int colsp) {
  int r = blockIdx.x;  // 0 .. 2*rows-1
  const float* s = (r < rows) ? (wl + (size_t)r * cols) : (wr + (size_t)(r - rows) * cols);
  for (int c = threadIdx.x; c < colsp; c += 256) {
    float v = (c < cols) ? s[c] : 0.f;
    o[(size_t)r * colsp + c] = (h16)v;
  }
}

__global__ __launch_bounds__(256) void attcvt_kernel(const float* __restrict__ a, h16* __restrict__ o, int n) {
  int i = blockIdx.x * 256 + threadIdx.x;
  if (i < n) o[i] = (h16)a[i];
}

// ---------- CSR build ----------
__global__ __launch_bounds__(256) void build_edges_kernel(const int* __restrict__ ei,
                                                          int* __restrict__ src, int* __restrict__ dst) {
  int e = blockIdx.x * 256 + threadIdx.x;
  if (e >= NE) return;
  if (e < NE0) { src[e] = ei[e]; dst[e] = ei[NE0 + e]; }
  else         { src[e] = e - NE0; dst[e] = e - NE0; }
}

__global__ __launch_bounds__(256) void deg_kernel(const int* __restrict__ dst, int* __restrict__ deg) {
  int e = blockIdx.x * 256 + threadIdx.x;
  if (e < NE) atomicAdd(&deg[dst[e]], 1);
}

__global__ __launch_bounds__(1024) void scan_kernel(const int* __restrict__ deg, int* __restrict__ rowptr) {
  __shared__ int b0[1024], b1[1024];
  __shared__ int carry;
  int t = threadIdx.x;
  if (t == 0) carry = 0;
  __syncthreads();
  for (int base = 0; base < NN; base += 1024) {
    int x = (base + t < NN) ? deg[base + t] : 0;
    b0[t] = x;
    __syncthreads();
    int* cur = b0; int* nxt = b1;
    for (int off = 1; off < 1024; off <<= 1) {
      int v = cur[t];
      if (t >= off) v += cur[t - off];
      nxt[t] = v;
      __syncthreads();
      int* tmp = cur; cur = nxt; nxt = tmp;
    }
    if (base + t < NN) rowptr[base + t] = carry + cur[t] - x;  // exclusive
    __syncthreads();
    if (t == 0) carry += cur[1023];
    __syncthreads();
  }
  if (t == 0) rowptr[NN] = carry;
}

__global__ __launch_bounds__(256) void scatter_kernel(const int* __restrict__ src, const int* __restrict__ dst,
                                                      const int* __restrict__ rowptr, int* __restrict__ cursor,
                                                      int* __restrict__ esrc) {
  int e = blockIdx.x * 256 + threadIdx.x;
  if (e >= NE) return;
  int d = dst[e];
  int pos = rowptr[d] + atomicAdd(&cursor[d], 1);
  esrc[pos] = src[e];
}

// ---------- fp16 MFMA GEMM, 256x256 tile, BK=32, 8 waves, 2 BLOCKS/CU ----------
// r7's proven counted-vmcnt double-buffer skeleton, BK 64->32 so LDS = 64 KiB
// -> 2 independent blocks per CU: their barrier drains / prologue loads /
// epilogue stores overlap each other (m114 mechanism, unavailable at 1 blk/CU).
// Bank swizzle re-derived for 64B row stride: f(row) = (row>>1)&3.
__global__ __launch_bounds__(512, 4) void gemm256_kernel(const h16* __restrict__ A, const h16* __restrict__ B,
                                                         h16* __restrict__ Co, int K, int Nw, int ntN) {
  __shared__ __align__(16) h16 lds[2 * 16384];  // [buf][A 256x32 | B 256x32]
  int nwg = gridDim.x;
  int q = nwg >> 3, r = nwg & 7;
  int xc = blockIdx.x & 7, idx = blockIdx.x >> 3;
  int logical = (xc < r ? xc * (q + 1) : r * (q + 1) + (xc - r) * q) + idx;
  int tm = (logical / ntN) * 256, tn = (logical % ntN) * 256;

  int tid = threadIdx.x;
  int wv = tid >> 6, lane = tid & 63;
  int wm = (wv >> 2) * 128, wn = (wv & 3) * 64;
  int lrow = lane & 15, kq = lane >> 4;
  int u = (kq ^ ((lrow >> 1) & 3)) * 8;  // swizzled read unit (h16 elems)

  // staging: thread t covers row j*128 + (tid>>6)*16 + ((tid&63)>>2), phys unit tid&3
  int rowoff = (tid >> 6) * 16 + ((tid & 63) >> 2);
  int ug = ((tid & 3) ^ ((tid >> 3) & 3)) * 8;  // pre-swizzled global unit (h16 elems)
  int ldsoff = (tid >> 6) * 512;                // wave-uniform LDS base (h16)

  const int NT = K >> 5;

  auto STAGE = [&](int buf, int kt) {
#pragma unroll
    for (int j = 0; j < 2; ++j) {
      GLDS16(A + (size_t)(tm + j * 128 + rowoff) * K + kt * 32 + ug,
             &lds[buf * 16384 + j * 4096 + ldsoff]);
      GLDS16(B + (size_t)(tn + j * 128 + rowoff) * K + kt * 32 + ug,
             &lds[buf * 16384 + 8192 + j * 4096 + ldsoff]);
    }
  };

  STAGE(0, 0);
  STAGE(1, 1);

  f32x4 acc[8][4] = {};
  for (int t = 0; t < NT; ++t) {
    int b = t & 1;
    if (t + 1 < NT) { asm volatile("s_waitcnt vmcnt(4)" ::: "memory"); }
    else            { asm volatile("s_waitcnt vmcnt(0)" ::: "memory"); }
    __builtin_amdgcn_s_barrier();  // buffer b landed for all waves

    const h16* As_ = &lds[b * 16384];
    const h16* Bs_ = &lds[b * 16384 + 8192];
    h16x8 af[8], bf[4];
#pragma unroll
    for (int i = 0; i < 8; ++i) af[i] = *(const h16x8*)&As_[(wm + i * 16 + lrow) * 32 + u];
#pragma unroll
    for (int j = 0; j < 4; ++j) bf[j] = *(const h16x8*)&Bs_[(wn + j * 16 + lrow) * 32 + u];
    asm volatile("s_waitcnt lgkmcnt(0)" ::: "memory");
    __builtin_amdgcn_sched_barrier(0);
    __builtin_amdgcn_s_barrier();  // all reads done -> safe to restage buffer b
    if (t + 2 < NT) STAGE(b, t + 2);
    __builtin_amdgcn_s_setprio(1);
#pragma unroll
    for (int i = 0; i < 8; ++i)
#pragma unroll
      for (int j = 0; j < 4; ++j)
        acc[i][j] = MFMA16(af[i], bf[j], acc[i][j]);
    __builtin_amdgcn_s_setprio(0);
  }

  int cr = kq * 4, cc = lrow;
#pragma unroll
  for (int i = 0; i < 8; ++i)
#pragma unroll
    for (int j = 0; j < 4; ++j) {
      size_t base = (size_t)(tm + wm + i * 16 + cr) * Nw + (tn + wn + j * 16 + cc);
#pragma unroll
      for (int qq = 0; qq < 4; qq++) Co[base + (size_t)qq * Nw] = (h16)acc[i][j][qq];
    }
}

// ---------- fused score + online-softmax + aggregate (r4-best: wave per head) ----------
// X row layout: [ xl (H*CD) | xr (H*CD) ], stride S = 2*H*CD.
template <int H, int MODE>
__global__ __launch_bounds__(64 * H) void sagg_kernel(
    const h16* __restrict__ X, const int* __restrict__ rowptr, const int* __restrict__ esrc,
    const h16* __restrict__ attH, const float* __restrict__ bias,
    h16* __restrict__ outA, const int* __restrict__ batch,
    float* __restrict__ pooled, int* __restrict__ cnt) {
  constexpr int HC = H * CD, S = 2 * HC;
  int n = blockIdx.x;
  int tid = threadIdx.x, w = tid >> 6, lane = tid & 63;
  int cb = w * CD + lane * 4;

  h16x4 aw4 = *(const h16x4*)(attH + cb);
  h16x2 alo = __builtin_shufflevector(aw4, aw4, 0, 1);
  h16x2 ahi = __builtin_shufflevector(aw4, aw4, 2, 3);
  h16x4 xr4 = *(const h16x4*)(X + (size_t)n * S + HC + cb);

  int beg = rowptr[n], end = rowptr[n + 1];
  float m = -1e30f, s = 0.f;
  f32x4 a = {};
  int i = beg;
  while (i < end) {
    int cn = end - i; if (cn > 8) cn = 8;
    int js[8];
    h16x4 xs[8];
    float ps[8];
#pragma unroll
    for (int k = 0; k < 8; ++k) js[k] = esrc[i + (k < cn ? k : cn - 1)];  // independent loads
#pragma unroll
    for (int k = 0; k < 8; ++k) xs[k] = *(const h16x4*)(X + (size_t)js[k] * S + cb);  // batched gathers
#pragma unroll
    for (int k = 0; k < 8; ++k) {
      h16x4 v = xs[k] + xr4;                       // v_pk_add_f16
      h16x4 t = v * (h16)SLOPE;                    // v_pk_mul_f16
      v = __builtin_elementwise_max(v, t);         // leaky_relu = max(x, 0.2x)
      float p = __builtin_amdgcn_fdot2(__builtin_shufflevector(v, v, 0, 1), alo,
                __builtin_amdgcn_fdot2(__builtin_shufflevector(v, v, 2, 3), ahi, 0.f, false), false);
      p += __shfl_xor(p, 32); p += __shfl_xor(p, 16); p += __shfl_xor(p, 8);
      p += __shfl_xor(p, 4);  p += __shfl_xor(p, 2);  p += __shfl_xor(p, 1);
      ps[k] = p;
    }
#pragma unroll
    for (int k = 0; k < 8; ++k) {
      if (k < cn) {
        float p = ps[k];
        if (p <= m) {            // wave-uniform branch: no rescale (common case)
          float we = __expf(p - m);
          s += we;
          a[0] += we * (float)xs[k][0]; a[1] += we * (float)xs[k][1];
          a[2] += we * (float)xs[k][2]; a[3] += we * (float)xs[k][3];
        } else {                 // new max: rescale, we = 1
          float f = __expf(m - p);
          s = s * f + 1.f;
          a[0] = a[0] * f + (float)xs[k][0]; a[1] = a[1] * f + (float)xs[k][1];
          a[2] = a[2] * f + (float)xs[k][2]; a[3] = a[3] * f + (float)xs[k][3];
          m = p;
        }
      }
    }
    i += cn;
  }
  float inv = 1.f / (s + 1e-16f);

  if (MODE == 0) {
    float o0 = a[0] * inv + bias[cb + 0];
    float o1 = a[1] * inv + bias[cb + 1];
    float o2 = a[2] * inv + bias[cb + 2];
    float o3 = a[3] * inv + bias[cb + 3];
    o0 = o0 > 0.f ? o0 : expm1f(o0);
    o1 = o1 > 0.f ? o1 : expm1f(o1);
    o2 = o2 > 0.f ? o2 : expm1f(o2);
    o3 = o3 > 0.f ? o3 : expm1f(o3);
    h16x4 ov = {(h16)o0, (h16)o1, (h16)o2, (h16)o3};
    *(h16x4*)(outA + (size_t)n * HC + cb) = ov;
  } else {
    __shared__ float sh[HC];
    __shared__ float red[H];
    float4 nv = {a[0] * inv, a[1] * inv, a[2] * inv, a[3] * inv};
    *(float4*)&sh[cb] = nv;
    __syncthreads();
    float mv = 0.f;
    if (tid < CD) {
#pragma unroll
      for (int h = 0; h < H; h++) mv += sh[h * CD + tid];
      mv = mv * (1.f / H) + bias[tid];
    }
    float ss = (tid < CD) ? mv * mv : 0.f;
    ss += __shfl_xor(ss, 32); ss += __shfl_xor(ss, 16); ss += __shfl_xor(ss, 8);
    ss += __shfl_xor(ss, 4);  ss += __shfl_xor(ss, 2);  ss += __shfl_xor(ss, 1);
    if (lane == 0) red[w] = ss;
    __syncthreads();
    float tot = 0.f;
#pragma unroll
    for (int h = 0; h < H; h++) tot += red[h];
    float scale = 1.f / fmaxf(sqrtf(tot), 1e-12f);
    int g = batch[n];
    if (tid < CD) atomicAdd(&pooled[(size_t)g * CD + tid], mv * scale);
    if (tid == 0) atomicAdd(&cnt[g], 1);
  }
}

// ---------- pooled epilogue ----------
__global__ __launch_bounds__(256) void pool_div_kernel(float* __restrict__ pooled, const int* __restrict__ cnt) {
  int g = blockIdx.x, t = threadIdx.x;
  pooled[(size_t)g * CD + t] /= fmaxf((float)cnt[g], 1.f);
}

__global__ __launch_bounds__(256) void mlp1_kernel(const float* __restrict__ pooled, const float* __restrict__ w,
                                                   const float* __restrict__ b, float* __restrict__ hid) {
  __shared__ float xs[CD];
  int g = blockIdx.x, t = threadIdx.x;
  xs[t] = pooled[(size_t)g * CD + t];
  __syncthreads();
  float acc = b[t];
  for (int k = 0; k < CD; ++k) acc += xs[k] * w[(size_t)t * CD + k];
  hid[(size_t)g * CD + t] = fmaxf(acc, 0.f);
}

__global__ __launch_bounds__(256) void mlp2_kernel(const float* __restrict__ hid, const float* __restrict__ w,
                                                   const float* __restrict__ b, float* __restrict__ out) {
  __shared__ float xs[CD];
  int g = blockIdx.x, t = threadIdx.x;
  xs[t] = hid[(size_t)g * CD + t];
  __syncthreads();
  for (int o = t; o < 768; o += 256) {
    float acc = b[o];
    for (int k = 0; k < CD; ++k) acc += xs[k] * w[(size_t)o * CD + k];
    out[(size_t)g * 768 + o] = acc;
  }
}

extern "C" void kernel_launch(void* const* d_in, const int* in_sizes, int n_in,
                              void* d_out, int out_size, void* d_ws, size_t ws_size,
                              hipStream_t stream) {
  const float* x      = (const float*)d_in[0];
  const int*   ei     = (const int*)d_in[1];
  const int*   batch  = (const int*)d_in[2];
  const float* c1_wl  = (const float*)d_in[3];
  const float* c1_wr  = (const float*)d_in[4];
  const float* c1_att = (const float*)d_in[5];
  const float* c1_b   = (const float*)d_in[6];
  const float* c2_wl  = (const float*)d_in[7];
  const float* c2_wr  = (const float*)d_in[8];
  const float* c2_att = (const float*)d_in[9];
  const float* c2_b   = (const float*)d_in[10];
  const float* c3_wl  = (const float*)d_in[11];
  const float* c3_wr  = (const float*)d_in[12];
  const float* c3_att = (const float*)d_in[13];
  const float* c3_b   = (const float*)d_in[14];
  const float* fp1_w  = (const float*)d_in[15];
  const float* fp1_b  = (const float*)d_in[16];
  const float* fp2_w  = (const float*)d_in[17];
  const float* fp2_b  = (const float*)d_in[18];

  char* p = (char*)d_ws;
  size_t off = 0;
  auto alloc = [&](size_t b) { void* r = p + off; off += (b + 255) & ~(size_t)255; return r; };
  h16*  A    = (h16*)alloc((size_t)NPAD * 1024 * 2);   // conv in/out feature buffer
  h16*  Xa   = (h16*)alloc((size_t)NPAD * 3072 * 2);   // X1 (2048 used) and X3 (3072)
  h16*  Xb   = (h16*)alloc((size_t)NPAD * 2048 * 2);   // X2; A1 aliases its head
  h16*  A1   = Xb;                                     // [NPAD][384] fp16 input (dead before X2 written)
  h16*  W1   = (h16*)alloc((size_t)2048 * K1P * 2);
  h16*  W2   = (h16*)alloc((size_t)2048 * 1024 * 2);
  h16*  W3   = (h16*)alloc((size_t)3072 * 1024 * 2);
  h16*  attH1 = (h16*)alloc((size_t)4 * CD * 2);
  h16*  attH2 = (h16*)alloc((size_t)4 * CD * 2);
  h16*  attH3 = (h16*)alloc((size_t)6 * CD * 2);
  int*  srcA   = (int*)alloc((size_t)NE * 4);
  int*  dstA   = (int*)alloc((size_t)NE * 4);
  int*  esrc   = (int*)alloc((size_t)NE * 4);
  int*  deg    = (int*)alloc((size_t)NN * 4);
  int*  cursor = (int*)alloc((size_t)NN * 4);
  int*  rowptr = (int*)alloc((size_t)(NN + 1) * 4);
  float* pooled = (float*)alloc((size_t)NG * CD * 4);
  int*  cnt    = (int*)alloc((size_t)NG * 4);
  float* hid   = (float*)alloc((size_t)NG * CD * 4);

  hipMemsetAsync(deg, 0, (size_t)NN * 4, stream);
  hipMemsetAsync(cursor, 0, (size_t)NN * 4, stream);
  hipMemsetAsync(pooled, 0, (size_t)NG * CD * 4, stream);
  hipMemsetAsync(cnt, 0, (size_t)NG * 4, stream);

  fill_x_kernel<<<NPAD, 256, 0, stream>>>(x, A1);
  conv_w2_kernel<<<2048, 256, 0, stream>>>(c1_wl, c1_wr, W1, 1024, FIN, K1P);
  conv_w2_kernel<<<2048, 256, 0, stream>>>(c2_wl, c2_wr, W2, 1024, 1024, 1024);
  conv_w2_kernel<<<3072, 256, 0, stream>>>(c3_wl, c3_wr, W3, 1536, 1024, 1024);
  attcvt_kernel<<<4, 256, 0, stream>>>(c1_att, attH1, 4 * CD);
  attcvt_kernel<<<4, 256, 0, stream>>>(c2_att, attH2, 4 * CD);
  attcvt_kernel<<<6, 256, 0, stream>>>(c3_att, attH3, 6 * CD);

  int eb = (NE + 255) / 256;
  build_edges_kernel<<<eb, 256, 0, stream>>>(ei, srcA, dstA);
  deg_kernel<<<eb, 256, 0, stream>>>(dstA, deg);
  scan_kernel<<<1, 1024, 0, stream>>>(deg, rowptr);
  scatter_kernel<<<eb, 256, 0, stream>>>(srcA, dstA, rowptr, cursor, esrc);

  // conv1: [NPAD,384] x [2048,384]^T -> Xa [NPAD,2048] = [XL|XR]
  gemm256_kernel<<<79 * 8, 512, 0, stream>>>(A1, W1, Xa, K1P, 2048, 8);
  sagg_kernel<4, 0><<<NN, 256, 0, stream>>>(Xa, rowptr, esrc, attH1, c1_b, A, nullptr, nullptr, nullptr);

  // conv2: [NPAD,1024] x [2048,1024]^T -> Xb
  gemm256_kernel<<<79 * 8, 512, 0, stream>>>(A, W2, Xb, 1024, 2048, 8);
  sagg_kernel<4, 0><<<NN, 256, 0, stream>>>(Xb, rowptr, esrc, attH2, c2_b, A, nullptr, nullptr, nullptr);

  // conv3: [NPAD,1024] x [3072,1024]^T -> Xa [NPAD,3072]
  gemm256_kernel<<<79 * 12, 512, 0, stream>>>(A, W3, Xa, 1024, 3072, 12);
  sagg_kernel<6, 1><<<NN, 384, 0, stream>>>(Xa, rowptr, esrc, attH3, c3_b, nullptr, batch, pooled, cnt);

  pool_div_kernel<<<NG, 256, 0, stream>>>(pooled, cnt);
  mlp1_kernel<<<NG, 256, 0, stream>>>(pooled, fp1_w, fp1_b, hid);
  mlp2_kernel<<<NG, 256, 0, stream>>>(hid, fp2_w, fp2_b, (float*)d_out);
}

// Round 13
// 700.628 us; speedup vs baseline: 4.9204x; 4.9204x over previous
//
#include <hip/hip_runtime.h>

typedef _Float16 h16;
typedef _Float16 h16x2 __attribute__((ext_vector_type(2)));
typedef _Float16 h16x4 __attribute__((ext_vector_type(4)));
typedef _Float16 h16x8 __attribute__((ext_vector_type(8)));
typedef float f32x4 __attribute__((ext_vector_type(4)));

static constexpr int NN   = 20000;   // nodes
static constexpr int NPAD = 20224;   // padded to 256-row tiles (79*256)
static constexpr int NE0  = 120000;  // raw edges
static constexpr int NE   = 140000;  // + self loops
static constexpr int NG   = 512;     // graphs
static constexpr int FIN  = 300;
static constexpr int K1P  = 384;     // FIN padded to K%64==0
static constexpr int CD   = 256;     // channels per head
static constexpr float SLOPE = 0.2f;

#define GLDS16(gsrc, ldst)                                                              \
  __builtin_amdgcn_global_load_lds(                                                    \
      (const __attribute__((address_space(1))) unsigned int*)(gsrc),                    \
      (__attribute__((address_space(3))) unsigned int*)(ldst), 16, 0, 0)

#define MFMA16(a, b, c) __builtin_amdgcn_mfma_f32_16x16x32_f16(a, b, c, 0, 0, 0)

// ---------- input conversion ----------
__global__ __launch_bounds__(256) void fill_x_kernel(const float* __restrict__ x, h16* __restrict__ a1) {
  int r = blockIdx.x;
  for (int c = threadIdx.x; c < K1P; c += 256) {
    float v = (r < NN && c < FIN) ? x[(size_t)r * FIN + c] : 0.f;
    a1[(size_t)r * K1P + c] = (h16)v;
  }
}

__global__ __launch_bounds__(256) void conv_w2_kernel(const float* __restrict__ wl, const float* __restrict__ wr,
                                                      h16* __restrict__ o, int rows, int cols, int colsp) {
  int r = blockIdx.x;  // 0 .. 2*rows-1
  const float* s = (r < rows) ? (wl + (size_t)r * cols) : (wr + (size_t)(r - rows) * cols);
  for (int c = threadIdx.x; c < colsp; c += 256) {
    float v = (c < cols) ? s[c] : 0.f;
    o[(size_t)r * colsp + c] = (h16)v;
  }
}

__global__ __launch_bounds__(256) void attcvt_kernel(const float* __restrict__ a, h16* __restrict__ o, int n) {
  int i = blockIdx.x * 256 + threadIdx.x;
  if (i < n) o[i] = (h16)a[i];
}

// ---------- CSR build ----------
__global__ __launch_bounds__(256) void build_edges_kernel(const int* __restrict__ ei,
                                                          int* __restrict__ src, int* __restrict__ dst) {
  int e = blockIdx.x * 256 + threadIdx.x;
  if (e >= NE) return;
  if (e < NE0) { src[e] = ei[e]; dst[e] = ei[NE0 + e]; }
  else         { src[e] = e - NE0; dst[e] = e - NE0; }
}

__global__ __launch_bounds__(256) void deg_kernel(const int* __restrict__ dst, int* __restrict__ deg) {
  int e = blockIdx.x * 256 + threadIdx.x;
  if (e < NE) atomicAdd(&deg[dst[e]], 1);
}

__global__ __launch_bounds__(1024) void scan_kernel(const int* __restrict__ deg, int* __restrict__ rowptr) {
  __shared__ int b0[1024], b1[1024];
  __shared__ int carry;
  int t = threadIdx.x;
  if (t == 0) carry = 0;
  __syncthreads();
  for (int base = 0; base < NN; base += 1024) {
    int x = (base + t < NN) ? deg[base + t] : 0;
    b0[t] = x;
    __syncthreads();
    int* cur = b0; int* nxt = b1;
    for (int off = 1; off < 1024; off <<= 1) {
      int v = cur[t];
      if (t >= off) v += cur[t - off];
      nxt[t] = v;
      __syncthreads();
      int* tmp = cur; cur = nxt; nxt = tmp;
    }
    if (base + t < NN) rowptr[base + t] = carry + cur[t] - x;  // exclusive
    __syncthreads();
    if (t == 0) carry += cur[1023];
    __syncthreads();
  }
  if (t == 0) rowptr[NN] = carry;
}

__global__ __launch_bounds__(256) void scatter_kernel(const int* __restrict__ src, const int* __restrict__ dst,
                                                      const int* __restrict__ rowptr, int* __restrict__ cursor,
                                                      int* __restrict__ esrc) {
  int e = blockIdx.x * 256 + threadIdx.x;
  if (e >= NE) return;
  int d = dst[e];
  int pos = rowptr[d] + atomicAdd(&cursor[d], 1);
  esrc[pos] = src[e];
}

// ---------- fp16 MFMA GEMM, 256x256 tile, BK=64, 8 waves ----------
// r7 counted-vmcnt double-buffer skeleton + m196's fine G-load||MFMA interleave:
// all 24 fragment reads up front -> early buffer-free barrier -> staging of
// K-tile t+2 spread 2-loads-per-16-MFMA across four sub-phases.
__global__ __launch_bounds__(512, 2) void gemm256_kernel(const h16* __restrict__ A, const h16* __restrict__ B,
                                                         h16* __restrict__ Co, int K, int Nw, int ntN) {
  __shared__ __align__(16) h16 lds[4 * 16384];  // [buf][mat] regions of 256x64
  int nwg = gridDim.x;
  int q = nwg >> 3, r = nwg & 7;
  int xc = blockIdx.x & 7, idx = blockIdx.x >> 3;
  int logical = (xc < r ? xc * (q + 1) : r * (q + 1) + (xc - r) * q) + idx;
  int tm = (logical / ntN) * 256, tn = (logical % ntN) * 256;

  int tid = threadIdx.x;
  int wv = tid >> 6, lane = tid & 63;
  int wm = (wv >> 2) * 128, wn = (wv & 3) * 64;
  int lrow = lane & 15, kq = lane >> 4, lr7 = lrow & 7;

  int rowoff = tid >> 3;
  int ug = ((tid & 7) ^ (rowoff & 7)) * 8;  // pre-swizzled global 16B-unit (in h16 elems)
  int ldsoff = (tid >> 6) * 512;

  const int NT = K >> 6;

  auto STAGE1 = [&](int buf, int kt, int j) {  // one A-issue + one B-issue (1/4 of a tile)
    GLDS16(A + (size_t)(tm + j * 64 + rowoff) * K + kt * 64 + ug,
           &lds[(buf * 2 + 0) * 16384 + j * 4096 + ldsoff]);
    GLDS16(B + (size_t)(tn + j * 64 + rowoff) * K + kt * 64 + ug,
           &lds[(buf * 2 + 1) * 16384 + j * 4096 + ldsoff]);
  };

#pragma unroll
  for (int j = 0; j < 4; ++j) STAGE1(0, 0, j);
#pragma unroll
  for (int j = 0; j < 4; ++j) STAGE1(1, 1, j);

  f32x4 acc[8][4] = {};
  for (int t = 0; t < NT; ++t) {
    int b = t & 1;
    if (t + 1 < NT) { asm volatile("s_waitcnt vmcnt(8)" ::: "memory"); }
    else            { asm volatile("s_waitcnt vmcnt(0)" ::: "memory"); }
    __builtin_amdgcn_s_barrier();  // buffer b landed for all waves

    const h16* As_ = &lds[(b * 2 + 0) * 16384];
    const h16* Bs_ = &lds[(b * 2 + 1) * 16384];
    int u0 = (kq ^ lr7) * 8;        // k-slice 0 unit
    int u1 = ((4 + kq) ^ lr7) * 8;  // k-slice 1 unit

    // read ALL fragments for this K-tile (both k-slices) into registers
    h16x8 af0[8], bf0[4], af1[8], bf1[4];
#pragma unroll
    for (int i = 0; i < 8; ++i) af0[i] = *(const h16x8*)&As_[(wm + i * 16 + lrow) * 64 + u0];
#pragma unroll
    for (int j = 0; j < 4; ++j) bf0[j] = *(const h16x8*)&Bs_[(wn + j * 16 + lrow) * 64 + u0];
#pragma unroll
    for (int i = 0; i < 8; ++i) af1[i] = *(const h16x8*)&As_[(wm + i * 16 + lrow) * 64 + u1];
#pragma unroll
    for (int j = 0; j < 4; ++j) bf1[j] = *(const h16x8*)&Bs_[(wn + j * 16 + lrow) * 64 + u1];
    asm volatile("s_waitcnt lgkmcnt(0)" ::: "memory");
    __builtin_amdgcn_sched_barrier(0);
    __builtin_amdgcn_s_barrier();  // all waves done reading buffer b -> safe to restage

    bool st = (t + 2 < NT);
    // ---- sub-phase 0: 2 stage loads + 16 MFMA (kslice0, cols 0-1)
    if (st) STAGE1(b, t + 2, 0);
    __builtin_amdgcn_s_setprio(1);
#pragma unroll
    for (int i = 0; i < 8; ++i) {
      acc[i][0] = MFMA16(af0[i], bf0[0], acc[i][0]);
      acc[i][1] = MFMA16(af0[i], bf0[1], acc[i][1]);
    }
    __builtin_amdgcn_s_setprio(0);
    __builtin_amdgcn_sched_barrier(0);
    // ---- sub-phase 1: 2 stage loads + 16 MFMA (kslice0, cols 2-3)
    if (st) STAGE1(b, t + 2, 1);
    __builtin_amdgcn_s_setprio(1);
#pragma unroll
    for (int i = 0; i < 8; ++i) {
      acc[i][2] = MFMA16(af0[i], bf0[2], acc[i][2]);
      acc[i][3] = MFMA16(af0[i], bf0[3], acc[i][3]);
    }
    __builtin_amdgcn_s_setprio(0);
    __builtin_amdgcn_sched_barrier(0);
    // ---- sub-phase 2: 2 stage loads + 16 MFMA (kslice1, cols 0-1)
    if (st) STAGE1(b, t + 2, 2);
    __builtin_amdgcn_s_setprio(1);
#pragma unroll
    for (int i = 0; i < 8; ++i) {
      acc[i][0] = MFMA16(af1[i], bf1[0], acc[i][0]);
      acc[i][1] = MFMA16(af1[i], bf1[1], acc[i][1]);
    }
    __builtin_amdgcn_s_setprio(0);
    __builtin_amdgcn_sched_barrier(0);
    // ---- sub-phase 3: 2 stage loads + 16 MFMA (kslice1, cols 2-3)
    if (st) STAGE1(b, t + 2, 3);
    __builtin_amdgcn_s_setprio(1);
#pragma unroll
    for (int i = 0; i < 8; ++i) {
      acc[i][2] = MFMA16(af1[i], bf1[2], acc[i][2]);
      acc[i][3] = MFMA16(af1[i], bf1[3], acc[i][3]);
    }
    __builtin_amdgcn_s_setprio(0);
  }

  int cr = kq * 4, cc = lrow;
#pragma unroll
  for (int i = 0; i < 8; ++i)
#pragma unroll
    for (int j = 0; j < 4; ++j) {
      size_t base = (size_t)(tm + wm + i * 16 + cr) * Nw + (tn + wn + j * 16 + cc);
#pragma unroll
      for (int qq = 0; qq < 4; qq++) Co[base + (size_t)qq * Nw] = (h16)acc[i][j][qq];
    }
}

// ---------- fused score + online-softmax + aggregate (r4-best: wave per head) ----------
// X row layout: [ xl (H*CD) | xr (H*CD) ], stride S = 2*H*CD.
template <int H, int MODE>
__global__ __launch_bounds__(64 * H) void sagg_kernel(
    const h16* __restrict__ X, const int* __restrict__ rowptr, const int* __restrict__ esrc,
    const h16* __restrict__ attH, const float* __restrict__ bias,
    h16* __restrict__ outA, const int* __restrict__ batch,
    float* __restrict__ pooled, int* __restrict__ cnt) {
  constexpr int HC = H * CD, S = 2 * HC;
  int n = blockIdx.x;
  int tid = threadIdx.x, w = tid >> 6, lane = tid & 63;
  int cb = w * CD + lane * 4;

  h16x4 aw4 = *(const h16x4*)(attH + cb);
  h16x2 alo = __builtin_shufflevector(aw4, aw4, 0, 1);
  h16x2 ahi = __builtin_shufflevector(aw4, aw4, 2, 3);
  h16x4 xr4 = *(const h16x4*)(X + (size_t)n * S + HC + cb);

  int beg = rowptr[n], end = rowptr[n + 1];
  float m = -1e30f, s = 0.f;
  f32x4 a = {};
  int i = beg;
  while (i < end) {
    int cn = end - i; if (cn > 8) cn = 8;
    int js[8];
    h16x4 xs[8];
    float ps[8];
#pragma unroll
    for (int k = 0; k < 8; ++k) js[k] = esrc[i + (k < cn ? k : cn - 1)];  // independent loads
#pragma unroll
    for (int k = 0; k < 8; ++k) xs[k] = *(const h16x4*)(X + (size_t)js[k] * S + cb);  // batched gathers
#pragma unroll
    for (int k = 0; k < 8; ++k) {
      h16x4 v = xs[k] + xr4;                       // v_pk_add_f16
      h16x4 t = v * (h16)SLOPE;                    // v_pk_mul_f16
      v = __builtin_elementwise_max(v, t);         // leaky_relu = max(x, 0.2x)
      float p = __builtin_amdgcn_fdot2(__builtin_shufflevector(v, v, 0, 1), alo,
                __builtin_amdgcn_fdot2(__builtin_shufflevector(v, v, 2, 3), ahi, 0.f, false), false);
      p += __shfl_xor(p, 32); p += __shfl_xor(p, 16); p += __shfl_xor(p, 8);
      p += __shfl_xor(p, 4);  p += __shfl_xor(p, 2);  p += __shfl_xor(p, 1);
      ps[k] = p;
    }
#pragma unroll
    for (int k = 0; k < 8; ++k) {
      if (k < cn) {
        float p = ps[k];
        if (p <= m) {            // wave-uniform branch: no rescale (common case)
          float we = __expf(p - m);
          s += we;
          a[0] += we * (float)xs[k][0]; a[1] += we * (float)xs[k][1];
          a[2] += we * (float)xs[k][2]; a[3] += we * (float)xs[k][3];
        } else {                 // new max: rescale, we = 1
          float f = __expf(m - p);
          s = s * f + 1.f;
          a[0] = a[0] * f + (float)xs[k][0]; a[1] = a[1] * f + (float)xs[k][1];
          a[2] = a[2] * f + (float)xs[k][2]; a[3] = a[3] * f + (float)xs[k][3];
          m = p;
        }
      }
    }
    i += cn;
  }
  float inv = 1.f / (s + 1e-16f);

  if (MODE == 0) {
    float o0 = a[0] * inv + bias[cb + 0];
    float o1 = a[1] * inv + bias[cb + 1];
    float o2 = a[2] * inv + bias[cb + 2];
    float o3 = a[3] * inv + bias[cb + 3];
    o0 = o0 > 0.f ? o0 : expm1f(o0);
    o1 = o1 > 0.f ? o1 : expm1f(o1);
    o2 = o2 > 0.f ? o2 : expm1f(o2);
    o3 = o3 > 0.f ? o3 : expm1f(o3);
    h16x4 ov = {(h16)o0, (h16)o1, (h16)o2, (h16)o3};
    *(h16x4*)(outA + (size_t)n * HC + cb) = ov;
  } else {
    __shared__ float sh[HC];
    __shared__ float red[H];
    float4 nv = {a[0] * inv, a[1] * inv, a[2] * inv, a[3] * inv};
    *(float4*)&sh[cb] = nv;
    __syncthreads();
    float mv = 0.f;
    if (tid < CD) {
#pragma unroll
      for (int h = 0; h < H; h++) mv += sh[h * CD + tid];
      mv = mv * (1.f / H) + bias[tid];
    }
    float ss = (tid < CD) ? mv * mv : 0.f;
    ss += __shfl_xor(ss, 32); ss += __shfl_xor(ss, 16); ss += __shfl_xor(ss, 8);
    ss += __shfl_xor(ss, 4);  ss += __shfl_xor(ss, 2);  ss += __shfl_xor(ss, 1);
    if (lane == 0) red[w] = ss;
    __syncthreads();
    float tot = 0.f;
#pragma unroll
    for (int h = 0; h < H; h++) tot += red[h];
    float scale = 1.f / fmaxf(sqrtf(tot), 1e-12f);
    int g = batch[n];
    if (tid < CD) atomicAdd(&pooled[(size_t)g * CD + tid], mv * scale);
    if (tid == 0) atomicAdd(&cnt[g], 1);
  }
}

// ---------- pooled epilogue ----------
__global__ __launch_bounds__(256) void pool_div_kernel(float* __restrict__ pooled, const int* __restrict__ cnt) {
  int g = blockIdx.x, t = threadIdx.x;
  pooled[(size_t)g * CD + t] /= fmaxf((float)cnt[g], 1.f);
}

__global__ __launch_bounds__(256) void mlp1_kernel(const float* __restrict__ pooled, const float* __restrict__ w,
                                                   const float* __restrict__ b, float* __restrict__ hid) {
  __shared__ float xs[CD];
  int g = blockIdx.x, t = threadIdx.x;
  xs[t] = pooled[(size_t)g * CD + t];
  __syncthreads();
  float acc = b[t];
  for (int k = 0; k < CD; ++k) acc += xs[k] * w[(size_t)t * CD + k];
  hid[(size_t)g * CD + t] = fmaxf(acc, 0.f);
}

__global__ __launch_bounds__(256) void mlp2_kernel(const float* __restrict__ hid, const float* __restrict__ w,
                                                   const float* __restrict__ b, float* __restrict__ out) {
  __shared__ float xs[CD];
  int g = blockIdx.x, t = threadIdx.x;
  xs[t] = hid[(size_t)g * CD + t];
  __syncthreads();
  for (int o = t; o < 768; o += 256) {
    float acc = b[o];
    for (int k = 0; k < CD; ++k) acc += xs[k] * w[(size_t)o * CD + k];
    out[(size_t)g * 768 + o] = acc;
  }
}

extern "C" void kernel_launch(void* const* d_in, const int* in_sizes, int n_in,
                              void* d_out, int out_size, void* d_ws, size_t ws_size,
                              hipStream_t stream) {
  const float* x      = (const float*)d_in[0];
  const int*   ei     = (const int*)d_in[1];
  const int*   batch  = (const int*)d_in[2];
  const float* c1_wl  = (const float*)d_in[3];
  const float* c1_wr  = (const float*)d_in[4];
  const float* c1_att = (const float*)d_in[5];
  const float* c1_b   = (const float*)d_in[6];
  const float* c2_wl  = (const float*)d_in[7];
  const float* c2_wr  = (const float*)d_in[8];
  const float* c2_att = (const float*)d_in[9];
  const float* c2_b   = (const float*)d_in[10];
  const float* c3_wl  = (const float*)d_in[11];
  const float* c3_wr  = (const float*)d_in[12];
  const float* c3_att = (const float*)d_in[13];
  const float* c3_b   = (const float*)d_in[14];
  const float* fp1_w  = (const float*)d_in[15];
  const float* fp1_b  = (const float*)d_in[16];
  const float* fp2_w  = (const float*)d_in[17];
  const float* fp2_b  = (const float*)d_in[18];

  char* p = (char*)d_ws;
  size_t off = 0;
  auto alloc = [&](size_t b) { void* r = p + off; off += (b + 255) & ~(size_t)255; return r; };
  h16*  A    = (h16*)alloc((size_t)NPAD * 1024 * 2);   // conv in/out feature buffer
  h16*  Xa   = (h16*)alloc((size_t)NPAD * 3072 * 2);   // X1 (2048 used) and X3 (3072)
  h16*  Xb   = (h16*)alloc((size_t)NPAD * 2048 * 2);   // X2; A1 aliases its head
  h16*  A1   = Xb;                                     // [NPAD][384] fp16 input (dead before X2 written)
  h16*  W1   = (h16*)alloc((size_t)2048 * K1P * 2);
  h16*  W2   = (h16*)alloc((size_t)2048 * 1024 * 2);
  h16*  W3   = (h16*)alloc((size_t)3072 * 1024 * 2);
  h16*  attH1 = (h16*)alloc((size_t)4 * CD * 2);
  h16*  attH2 = (h16*)alloc((size_t)4 * CD * 2);
  h16*  attH3 = (h16*)alloc((size_t)6 * CD * 2);
  int*  srcA   = (int*)alloc((size_t)NE * 4);
  int*  dstA   = (int*)alloc((size_t)NE * 4);
  int*  esrc   = (int*)alloc((size_t)NE * 4);
  int*  deg    = (int*)alloc((size_t)NN * 4);
  int*  cursor = (int*)alloc((size_t)NN * 4);
  int*  rowptr = (int*)alloc((size_t)(NN + 1) * 4);
  float* pooled = (float*)alloc((size_t)NG * CD * 4);
  int*  cnt    = (int*)alloc((size_t)NG * 4);
  float* hid   = (float*)alloc((size_t)NG * CD * 4);

  hipMemsetAsync(deg, 0, (size_t)NN * 4, stream);
  hipMemsetAsync(cursor, 0, (size_t)NN * 4, stream);
  hipMemsetAsync(pooled, 0, (size_t)NG * CD * 4, stream);
  hipMemsetAsync(cnt, 0, (size_t)NG * 4, stream);

  fill_x_kernel<<<NPAD, 256, 0, stream>>>(x, A1);
  conv_w2_kernel<<<2048, 256, 0, stream>>>(c1_wl, c1_wr, W1, 1024, FIN, K1P);
  conv_w2_kernel<<<2048, 256, 0, stream>>>(c2_wl, c2_wr, W2, 1024, 1024, 1024);
  conv_w2_kernel<<<3072, 256, 0, stream>>>(c3_wl, c3_wr, W3, 1536, 1024, 1024);
  attcvt_kernel<<<4, 256, 0, stream>>>(c1_att, attH1, 4 * CD);
  attcvt_kernel<<<4, 256, 0, stream>>>(c2_att, attH2, 4 * CD);
  attcvt_kernel<<<6, 256, 0, stream>>>(c3_att, attH3, 6 * CD);

  int eb = (NE + 255) / 256;
  build_edges_kernel<<<eb, 256, 0, stream>>>(ei, srcA, dstA);
  deg_kernel<<<eb, 256, 0, stream>>>(dstA, deg);
  scan_kernel<<<1, 1024, 0, stream>>>(deg, rowptr);
  scatter_kernel<<<eb, 256, 0, stream>>>(srcA, dstA, rowptr, cursor, esrc);

  // conv1: [NPAD,384] x [2048,384]^T -> Xa [NPAD,2048] = [XL|XR]
  gemm256_kernel<<<79 * 8, 512, 0, stream>>>(A1, W1, Xa, K1P, 2048, 8);
  sagg_kernel<4, 0><<<NN, 256, 0, stream>>>(Xa, rowptr, esrc, attH1, c1_b, A, nullptr, nullptr, nullptr);

  // conv2: [NPAD,1024] x [2048,1024]^T -> Xb
  gemm256_kernel<<<79 * 8, 512, 0, stream>>>(A, W2, Xb, 1024, 2048, 8);
  sagg_kernel<4, 0><<<NN, 256, 0, stream>>>(Xb, rowptr, esrc, attH2, c2_b, A, nullptr, nullptr, nullptr);

  // conv3: [NPAD,1024] x [3072,1024]^T -> Xa [NPAD,3072]
  gemm256_kernel<<<79 * 12, 512, 0, stream>>>(A, W3, Xa, 1024, 3072, 12);
  sagg_kernel<6, 1><<<NN, 384, 0, stream>>>(Xa, rowptr, esrc, attH3, c3_b, nullptr, batch, pooled, cnt);

  pool_div_kernel<<<NG, 256, 0, stream>>>(pooled, cnt);
  mlp1_kernel<<<NG, 256, 0, stream>>>(pooled, fp1_w, fp1_b, hid);
  mlp2_kernel<<<NG, 256, 0, stream>>>(hid, fp2_w, fp2_b, (float*)d_out);
}

// Round 14
// 695.114 us; speedup vs baseline: 4.9595x; 1.0079x over previous
//
#include <hip/hip_runtime.h>

typedef _Float16 h16;
typedef _Float16 h16x2 __attribute__((ext_vector_type(2)));
typedef _Float16 h16x4 __attribute__((ext_vector_type(4)));
typedef _Float16 h16x8 __attribute__((ext_vector_type(8)));
typedef float f32x4 __attribute__((ext_vector_type(4)));

static constexpr int NN   = 20000;   // nodes
static constexpr int NPAD = 20224;   // padded to 256-row tiles (79*256)
static constexpr int NE0  = 120000;  // raw edges
static constexpr int NE   = 140000;  // + self loops
static constexpr int NG   = 512;     // graphs
static constexpr int FIN  = 300;
static constexpr int K1P  = 320;     // FIN padded to K%64==0 (5 BK-iters)
static constexpr int CD   = 256;     // channels per head
static constexpr float SLOPE = 0.2f;

#define GLDS16(gsrc, ldst)                                                              \
  __builtin_amdgcn_global_load_lds(                                                    \
      (const __attribute__((address_space(1))) unsigned int*)(gsrc),                    \
      (__attribute__((address_space(3))) unsigned int*)(ldst), 16, 0, 0)

#define MFMA16(a, b, c) __builtin_amdgcn_mfma_f32_16x16x32_f16(a, b, c, 0, 0, 0)

// ---------- input conversion ----------
__global__ __launch_bounds__(256) void fill_x_kernel(const float* __restrict__ x, h16* __restrict__ a1) {
  int r = blockIdx.x;
  for (int c = threadIdx.x; c < K1P; c += 256) {
    float v = (r < NN && c < FIN) ? x[(size_t)r * FIN + c] : 0.f;
    a1[(size_t)r * K1P + c] = (h16)v;
  }
}

__global__ __launch_bounds__(256) void conv_w2_kernel(const float* __restrict__ wl, const float* __restrict__ wr,
                                                      h16* __restrict__ o, int rows, int cols, int colsp) {
  int r = blockIdx.x;  // 0 .. 2*rows-1
  const float* s = (r < rows) ? (wl + (size_t)r * cols) : (wr + (size_t)(r - rows) * cols);
  for (int c = threadIdx.x; c < colsp; c += 256) {
    float v = (c < cols) ? s[c] : 0.f;
    o[(size_t)r * colsp + c] = (h16)v;
  }
}

__global__ __launch_bounds__(256) void attcvt_kernel(const float* __restrict__ a, h16* __restrict__ o, int n) {
  int i = blockIdx.x * 256 + threadIdx.x;
  if (i < n) o[i] = (h16)a[i];
}

// ---------- CSR build ----------
__global__ __launch_bounds__(256) void build_edges_kernel(const int* __restrict__ ei,
                                                          int* __restrict__ src, int* __restrict__ dst) {
  int e = blockIdx.x * 256 + threadIdx.x;
  if (e >= NE) return;
  if (e < NE0) { src[e] = ei[e]; dst[e] = ei[NE0 + e]; }
  else         { src[e] = e - NE0; dst[e] = e - NE0; }
}

__global__ __launch_bounds__(256) void deg_kernel(const int* __restrict__ dst, int* __restrict__ deg) {
  int e = blockIdx.x * 256 + threadIdx.x;
  if (e < NE) atomicAdd(&deg[dst[e]], 1);
}

__global__ __launch_bounds__(1024) void scan_kernel(const int* __restrict__ deg, int* __restrict__ rowptr) {
  __shared__ int b0[1024], b1[1024];
  __shared__ int carry;
  int t = threadIdx.x;
  if (t == 0) carry = 0;
  __syncthreads();
  for (int base = 0; base < NN; base += 1024) {
    int x = (base + t < NN) ? deg[base + t] : 0;
    b0[t] = x;
    __syncthreads();
    int* cur = b0; int* nxt = b1;
    for (int off = 1; off < 1024; off <<= 1) {
      int v = cur[t];
      if (t >= off) v += cur[t - off];
      nxt[t] = v;
      __syncthreads();
      int* tmp = cur; cur = nxt; nxt = tmp;
    }
    if (base + t < NN) rowptr[base + t] = carry + cur[t] - x;  // exclusive
    __syncthreads();
    if (t == 0) carry += cur[1023];
    __syncthreads();
  }
  if (t == 0) rowptr[NN] = carry;
}

__global__ __launch_bounds__(256) void scatter_kernel(const int* __restrict__ src, const int* __restrict__ dst,
                                                      const int* __restrict__ rowptr, int* __restrict__ cursor,
                                                      int* __restrict__ esrc) {
  int e = blockIdx.x * 256 + threadIdx.x;
  if (e >= NE) return;
  int d = dst[e];
  int pos = rowptr[d] + atomicAdd(&cursor[d], 1);
  esrc[pos] = src[e];
}

// ---------- fp16 MFMA GEMM, 256x256 tile, BK=64, 8 waves (r7-best, monolithic) ----------
// Counted-vmcnt double-buffer: gate vmcnt(8) keeps next tile's loads in flight
// across barriers; monolithic 24-read + 64-MFMA compute region (best measured:
// 142us conv2; all finer-grained schedule variants were null or worse, r9-r13).
__global__ __launch_bounds__(512, 2) void gemm256_kernel(const h16* __restrict__ A, const h16* __restrict__ B,
                                                         h16* __restrict__ Co, int K, int Nw, int ntN) {
  __shared__ __align__(16) h16 lds[4 * 16384];  // [buf][mat] regions of 256x64
  int nwg = gridDim.x;
  int q = nwg >> 3, r = nwg & 7;
  int xc = blockIdx.x & 7, idx = blockIdx.x >> 3;
  int logical = (xc < r ? xc * (q + 1) : r * (q + 1) + (xc - r) * q) + idx;
  int tm = (logical / ntN) * 256, tn = (logical % ntN) * 256;

  int tid = threadIdx.x;
  int wv = tid >> 6, lane = tid & 63;
  int wm = (wv >> 2) * 128, wn = (wv & 3) * 64;
  int lrow = lane & 15, kq = lane >> 4, lr7 = lrow & 7;

  int rowoff = tid >> 3;
  int ug = ((tid & 7) ^ (rowoff & 7)) * 8;  // pre-swizzled global 16B-unit (in h16 elems)
  int ldsoff = (tid >> 6) * 512;

  const int NT = K >> 6;

  auto STAGE = [&](int buf, int kt) {
#pragma unroll
    for (int j = 0; j < 4; ++j) {
      GLDS16(A + (size_t)(tm + j * 64 + rowoff) * K + kt * 64 + ug,
             &lds[(buf * 2 + 0) * 16384 + j * 4096 + ldsoff]);
      GLDS16(B + (size_t)(tn + j * 64 + rowoff) * K + kt * 64 + ug,
             &lds[(buf * 2 + 1) * 16384 + j * 4096 + ldsoff]);
    }
  };

  STAGE(0, 0);
  STAGE(1, 1);

  f32x4 acc[8][4] = {};
  for (int t = 0; t < NT; ++t) {
    int b = t & 1;
    if (t + 1 < NT) { asm volatile("s_waitcnt vmcnt(8)" ::: "memory"); }
    else            { asm volatile("s_waitcnt vmcnt(0)" ::: "memory"); }
    __builtin_amdgcn_s_barrier();  // all waves' portions of buffer b have landed

    const h16* As_ = &lds[(b * 2 + 0) * 16384];
    const h16* Bs_ = &lds[(b * 2 + 1) * 16384];
    h16x8 af[8], bf[4];
#pragma unroll
    for (int i = 0; i < 8; ++i) af[i] = *(const h16x8*)&As_[(wm + i * 16 + lrow) * 64 + ((kq ^ lr7) * 8)];
#pragma unroll
    for (int j = 0; j < 4; ++j) bf[j] = *(const h16x8*)&Bs_[(wn + j * 16 + lrow) * 64 + ((kq ^ lr7) * 8)];
#pragma unroll
    for (int i = 0; i < 8; ++i)
#pragma unroll
      for (int j = 0; j < 4; ++j)
        acc[i][j] = MFMA16(af[i], bf[j], acc[i][j]);
#pragma unroll
    for (int i = 0; i < 8; ++i) af[i] = *(const h16x8*)&As_[(wm + i * 16 + lrow) * 64 + (((4 + kq) ^ lr7) * 8)];
#pragma unroll
    for (int j = 0; j < 4; ++j) bf[j] = *(const h16x8*)&Bs_[(wn + j * 16 + lrow) * 64 + (((4 + kq) ^ lr7) * 8)];
    asm volatile("s_waitcnt lgkmcnt(0)" ::: "memory");
    __builtin_amdgcn_sched_barrier(0);
    __builtin_amdgcn_s_barrier();  // all waves done reading buffer b -> safe to restage
    if (t + 2 < NT) STAGE(b, t + 2);
    __builtin_amdgcn_s_setprio(1);
#pragma unroll
    for (int i = 0; i < 8; ++i)
#pragma unroll
      for (int j = 0; j < 4; ++j)
        acc[i][j] = MFMA16(af[i], bf[j], acc[i][j]);
    __builtin_amdgcn_s_setprio(0);
  }

  int cr = kq * 4, cc = lrow;
#pragma unroll
  for (int i = 0; i < 8; ++i)
#pragma unroll
    for (int j = 0; j < 4; ++j) {
      size_t base = (size_t)(tm + wm + i * 16 + cr) * Nw + (tn + wn + j * 16 + cc);
#pragma unroll
      for (int qq = 0; qq < 4; qq++) Co[base + (size_t)qq * Nw] = (h16)acc[i][j][qq];
    }
}

// ---------- fused score + online-softmax + aggregate (r4-best: wave per head) ----------
// X row layout: [ xl (H*CD) | xr (H*CD) ], stride S = 2*H*CD.
template <int H, int MODE>
__global__ __launch_bounds__(64 * H) void sagg_kernel(
    const h16* __restrict__ X, const int* __restrict__ rowptr, const int* __restrict__ esrc,
    const h16* __restrict__ attH, const float* __restrict__ bias,
    h16* __restrict__ outA, const int* __restrict__ batch,
    float* __restrict__ pooled, int* __restrict__ cnt) {
  constexpr int HC = H * CD, S = 2 * HC;
  int n = blockIdx.x;
  int tid = threadIdx.x, w = tid >> 6, lane = tid & 63;
  int cb = w * CD + lane * 4;

  h16x4 aw4 = *(const h16x4*)(attH + cb);
  h16x2 alo = __builtin_shufflevector(aw4, aw4, 0, 1);
  h16x2 ahi = __builtin_shufflevector(aw4, aw4, 2, 3);
  h16x4 xr4 = *(const h16x4*)(X + (size_t)n * S + HC + cb);

  int beg = rowptr[n], end = rowptr[n + 1];
  float m = -1e30f, s = 0.f;
  f32x4 a = {};
  int i = beg;
  while (i < end) {
    int cn = end - i; if (cn > 8) cn = 8;
    int js[8];
    h16x4 xs[8];
    float ps[8];
#pragma unroll
    for (int k = 0; k < 8; ++k) js[k] = esrc[i + (k < cn ? k : cn - 1)];  // independent loads
#pragma unroll
    for (int k = 0; k < 8; ++k) xs[k] = *(const h16x4*)(X + (size_t)js[k] * S + cb);  // batched gathers
#pragma unroll
    for (int k = 0; k < 8; ++k) {
      h16x4 v = xs[k] + xr4;                       // v_pk_add_f16
      h16x4 t = v * (h16)SLOPE;                    // v_pk_mul_f16
      v = __builtin_elementwise_max(v, t);         // leaky_relu = max(x, 0.2x)
      float p = __builtin_amdgcn_fdot2(__builtin_shufflevector(v, v, 0, 1), alo,
                __builtin_amdgcn_fdot2(__builtin_shufflevector(v, v, 2, 3), ahi, 0.f, false), false);
      p += __shfl_xor(p, 32); p += __shfl_xor(p, 16); p += __shfl_xor(p, 8);
      p += __shfl_xor(p, 4);  p += __shfl_xor(p, 2);  p += __shfl_xor(p, 1);
      ps[k] = p;
    }
#pragma unroll
    for (int k = 0; k < 8; ++k) {
      if (k < cn) {
        float p = ps[k];
        if (p <= m) {            // wave-uniform branch: no rescale (common case)
          float we = __expf(p - m);
          s += we;
          a[0] += we * (float)xs[k][0]; a[1] += we * (float)xs[k][1];
          a[2] += we * (float)xs[k][2]; a[3] += we * (float)xs[k][3];
        } else {                 // new max: rescale, we = 1
          float f = __expf(m - p);
          s = s * f + 1.f;
          a[0] = a[0] * f + (float)xs[k][0]; a[1] = a[1] * f + (float)xs[k][1];
          a[2] = a[2] * f + (float)xs[k][2]; a[3] = a[3] * f + (float)xs[k][3];
          m = p;
        }
      }
    }
    i += cn;
  }
  float inv = 1.f / (s + 1e-16f);

  if (MODE == 0) {
    float o0 = a[0] * inv + bias[cb + 0];
    float o1 = a[1] * inv + bias[cb + 1];
    float o2 = a[2] * inv + bias[cb + 2];
    float o3 = a[3] * inv + bias[cb + 3];
    o0 = o0 > 0.f ? o0 : expm1f(o0);
    o1 = o1 > 0.f ? o1 : expm1f(o1);
    o2 = o2 > 0.f ? o2 : expm1f(o2);
    o3 = o3 > 0.f ? o3 : expm1f(o3);
    h16x4 ov = {(h16)o0, (h16)o1, (h16)o2, (h16)o3};
    *(h16x4*)(outA + (size_t)n * HC + cb) = ov;
  } else {
    __shared__ float sh[HC];
    __shared__ float red[H];
    float4 nv = {a[0] * inv, a[1] * inv, a[2] * inv, a[3] * inv};
    *(float4*)&sh[cb] = nv;
    __syncthreads();
    float mv = 0.f;
    if (tid < CD) {
#pragma unroll
      for (int h = 0; h < H; h++) mv += sh[h * CD + tid];
      mv = mv * (1.f / H) + bias[tid];
    }
    float ss = (tid < CD) ? mv * mv : 0.f;
    ss += __shfl_xor(ss, 32); ss += __shfl_xor(ss, 16); ss += __shfl_xor(ss, 8);
    ss += __shfl_xor(ss, 4);  ss += __shfl_xor(ss, 2);  ss += __shfl_xor(ss, 1);
    if (lane == 0) red[w] = ss;
    __syncthreads();
    float tot = 0.f;
#pragma unroll
    for (int h = 0; h < H; h++) tot += red[h];
    float scale = 1.f / fmaxf(sqrtf(tot), 1e-12f);
    int g = batch[n];
    if (tid < CD) atomicAdd(&pooled[(size_t)g * CD + tid], mv * scale);
    if (tid == 0) atomicAdd(&cnt[g], 1);
  }
}

// ---------- pooled epilogue ----------
__global__ __launch_bounds__(256) void pool_div_kernel(float* __restrict__ pooled, const int* __restrict__ cnt) {
  int g = blockIdx.x, t = threadIdx.x;
  pooled[(size_t)g * CD + t] /= fmaxf((float)cnt[g], 1.f);
}

__global__ __launch_bounds__(256) void mlp1_kernel(const float* __restrict__ pooled, const float* __restrict__ w,
                                                   const float* __restrict__ b, float* __restrict__ hid) {
  __shared__ float xs[CD];
  int g = blockIdx.x, t = threadIdx.x;
  xs[t] = pooled[(size_t)g * CD + t];
  __syncthreads();
  float acc = b[t];
  for (int k = 0; k < CD; ++k) acc += xs[k] * w[(size_t)t * CD + k];
  hid[(size_t)g * CD + t] = fmaxf(acc, 0.f);
}

__global__ __launch_bounds__(256) void mlp2_kernel(const float* __restrict__ hid, const float* __restrict__ w,
                                                   const float* __restrict__ b, float* __restrict__ out) {
  __shared__ float xs[CD];
  int g = blockIdx.x, t = threadIdx.x;
  xs[t] = hid[(size_t)g * CD + t];
  __syncthreads();
  for (int o = t; o < 768; o += 256) {
    float acc = b[o];
    for (int k = 0; k < CD; ++k) acc += xs[k] * w[(size_t)o * CD + k];
    out[(size_t)g * 768 + o] = acc;
  }
}

extern "C" void kernel_launch(void* const* d_in, const int* in_sizes, int n_in,
                              void* d_out, int out_size, void* d_ws, size_t ws_size,
                              hipStream_t stream) {
  const float* x      = (const float*)d_in[0];
  const int*   ei     = (const int*)d_in[1];
  const int*   batch  = (const int*)d_in[2];
  const float* c1_wl  = (const float*)d_in[3];
  const float* c1_wr  = (const float*)d_in[4];
  const float* c1_att = (const float*)d_in[5];
  const float* c1_b   = (const float*)d_in[6];
  const float* c2_wl  = (const float*)d_in[7];
  const float* c2_wr  = (const float*)d_in[8];
  const float* c2_att = (const float*)d_in[9];
  const float* c2_b   = (const float*)d_in[10];
  const float* c3_wl  = (const float*)d_in[11];
  const float* c3_wr  = (const float*)d_in[12];
  const float* c3_att = (const float*)d_in[13];
  const float* c3_b   = (const float*)d_in[14];
  const float* fp1_w  = (const float*)d_in[15];
  const float* fp1_b  = (const float*)d_in[16];
  const float* fp2_w  = (const float*)d_in[17];
  const float* fp2_b  = (const float*)d_in[18];

  char* p = (char*)d_ws;
  size_t off = 0;
  auto alloc = [&](size_t b) { void* r = p + off; off += (b + 255) & ~(size_t)255; return r; };
  h16*  A    = (h16*)alloc((size_t)NPAD * 1024 * 2);   // conv in/out feature buffer
  h16*  Xa   = (h16*)alloc((size_t)NPAD * 3072 * 2);   // X1 (2048 used) and X3 (3072)
  h16*  Xb   = (h16*)alloc((size_t)NPAD * 2048 * 2);   // X2; A1 aliases its head
  h16*  A1   = Xb;                                     // [NPAD][320] fp16 input (dead before X2 written)
  h16*  W1   = (h16*)alloc((size_t)2048 * K1P * 2);
  h16*  W2   = (h16*)alloc((size_t)2048 * 1024 * 2);
  h16*  W3   = (h16*)alloc((size_t)3072 * 1024 * 2);
  h16*  attH1 = (h16*)alloc((size_t)4 * CD * 2);
  h16*  attH2 = (h16*)alloc((size_t)4 * CD * 2);
  h16*  attH3 = (h16*)alloc((size_t)6 * CD * 2);
  int*  srcA   = (int*)alloc((size_t)NE * 4);
  int*  dstA   = (int*)alloc((size_t)NE * 4);
  int*  esrc   = (int*)alloc((size_t)NE * 4);
  int*  deg    = (int*)alloc((size_t)NN * 4);
  int*  cursor = (int*)alloc((size_t)NN * 4);
  int*  rowptr = (int*)alloc((size_t)(NN + 1) * 4);
  float* pooled = (float*)alloc((size_t)NG * CD * 4);
  int*  cnt    = (int*)alloc((size_t)NG * 4);
  float* hid   = (float*)alloc((size_t)NG * CD * 4);

  hipMemsetAsync(deg, 0, (size_t)NN * 4, stream);
  hipMemsetAsync(cursor, 0, (size_t)NN * 4, stream);
  hipMemsetAsync(pooled, 0, (size_t)NG * CD * 4, stream);
  hipMemsetAsync(cnt, 0, (size_t)NG * 4, stream);

  fill_x_kernel<<<NPAD, 256, 0, stream>>>(x, A1);
  conv_w2_kernel<<<2048, 256, 0, stream>>>(c1_wl, c1_wr, W1, 1024, FIN, K1P);
  conv_w2_kernel<<<2048, 256, 0, stream>>>(c2_wl, c2_wr, W2, 1024, 1024, 1024);
  conv_w2_kernel<<<3072, 256, 0, stream>>>(c3_wl, c3_wr, W3, 1536, 1024, 1024);
  attcvt_kernel<<<4, 256, 0, stream>>>(c1_att, attH1, 4 * CD);
  attcvt_kernel<<<4, 256, 0, stream>>>(c2_att, attH2, 4 * CD);
  attcvt_kernel<<<6, 256, 0, stream>>>(c3_att, attH3, 6 * CD);

  int eb = (NE + 255) / 256;
  build_edges_kernel<<<eb, 256, 0, stream>>>(ei, srcA, dstA);
  deg_kernel<<<eb, 256, 0, stream>>>(dstA, deg);
  scan_kernel<<<1, 1024, 0, stream>>>(deg, rowptr);
  scatter_kernel<<<eb, 256, 0, stream>>>(srcA, dstA, rowptr, cursor, esrc);

  // conv1: [NPAD,320] x [2048,320]^T -> Xa [NPAD,2048] = [XL|XR]
  gemm256_kernel<<<79 * 8, 512, 0, stream>>>(A1, W1, Xa, K1P, 2048, 8);
  sagg_kernel<4, 0><<<NN, 256, 0, stream>>>(Xa, rowptr, esrc, attH1, c1_b, A, nullptr, nullptr, nullptr);

  // conv2: [NPAD,1024] x [2048,1024]^T -> Xb
  gemm256_kernel<<<79 * 8, 512, 0, stream>>>(A, W2, Xb, 1024, 2048, 8);
  sagg_kernel<4, 0><<<NN, 256, 0, stream>>>(Xb, rowptr, esrc, attH2, c2_b, A, nullptr, nullptr, nullptr);

  // conv3: [NPAD,1024] x [3072,1024]^T -> Xa [NPAD,3072]
  gemm256_kernel<<<79 * 12, 512, 0, stream>>>(A, W3, Xa, 1024, 3072, 12);
  sagg_kernel<6, 1><<<NN, 384, 0, stream>>>(Xa, rowptr, esrc, attH3, c3_b, nullptr, batch, pooled, cnt);

  pool_div_kernel<<<NG, 256, 0, stream>>>(pooled, cnt);
  mlp1_kernel<<<NG, 256, 0, stream>>>(pooled, fp1_w, fp1_b, hid);
  mlp2_kernel<<<NG, 256, 0, stream>>>(hid, fp2_w, fp2_b, (float*)d_out);
}